// Round 4
// baseline (82.584 us; speedup 1.0000x reference)
//
#include <hip/hip_runtime.h>

#define NSEQ 32
#define NH 32
#define NKV 8
#define GRP 4
#define HD 128
#define BS 16
#define MAXCTX 2048
#define BPS 128
#define CHUNK 128
#define NSPLIT (MAXCTX / CHUNK)   // 16
#define SCALE 0.08838834764831845f

__device__ __forceinline__ float dot8(float4 qa, float4 qb, float4 ka, float4 kb) {
  float r = qa.x * ka.x;
  r = fmaf(qa.y, ka.y, r);
  r = fmaf(qa.z, ka.z, r);
  r = fmaf(qa.w, ka.w, r);
  r = fmaf(qb.x, kb.x, r);
  r = fmaf(qb.y, kb.y, r);
  r = fmaf(qb.z, kb.z, r);
  r = fmaf(qb.w, kb.w, r);
  return r;
}

__device__ __forceinline__ float red16(float x) {
  x += __shfl_xor(x, 1);
  x += __shfl_xor(x, 2);
  x += __shfl_xor(x, 4);
  x += __shfl_xor(x, 8);
  return x;
}

__device__ __forceinline__ void red_sub(float4& v) {
  v.x += __shfl_xor(v.x, 16); v.y += __shfl_xor(v.y, 16);
  v.z += __shfl_xor(v.z, 16); v.w += __shfl_xor(v.w, 16);
  v.x += __shfl_xor(v.x, 32); v.y += __shfl_xor(v.y, 32);
  v.z += __shfl_xor(v.z, 32); v.w += __shfl_xor(v.w, 32);
}

// One workgroup per (kv-head, seq, ctx-split). Produces an UNNORMALIZED
// partial (m, l, acc[GRP][HD]) for its 128-token chunk, flash-decode style.
extern "C" __global__ __launch_bounds__(256, 8)
void paged_split(const float* __restrict__ q,
                 const float* __restrict__ k_new,
                 const float* __restrict__ v_new,
                 const float* __restrict__ k_cache,
                 const float* __restrict__ v_cache,
                 const float* __restrict__ cos_cache,
                 const float* __restrict__ sin_cache,
                 const int* __restrict__ block_tables,
                 const int* __restrict__ context_lens,
                 float* __restrict__ accW,
                 float2* __restrict__ mlW)
{
  const int kv = blockIdx.x;   // 0..7
  const int s  = blockIdx.y;   // 0..31
  const int sp = blockIdx.z;   // 0..15
  const int ctx = context_lens[s];
  const int t0  = sp * CHUNK;
  if (t0 >= ctx) return;                      // inactive split: never read by reduce
  const int tend = min(t0 + CHUNK, ctx);
  const int ntok = tend - t0;                 // tokens this split handles (incl. new)
  const int pos  = ctx - 1;                   // the new token's position
  const bool has_new = (pos >= t0) && (pos < tend);   // ONLY the split containing ctx-1
  const int ncache = has_new ? (pos - t0) : ntok;     // local cache-token count

  const int tid  = threadIdx.x;
  const int lane = tid & 63;
  const int w    = tid >> 6;
  const int sub  = lane >> 4;
  const int li   = lane & 15;

  __shared__ float cs_lds[64];
  __shared__ float sn_lds[64];
  __shared__ float qrot[GRP * HD];       // 2 KB
  __shared__ float krot[HD];             // 512 B
  __shared__ int   bt[CHUNK / BS];       // 8 entries
  __shared__ float s_sc[GRP][CHUNK];     // 2 KB (scores -> p)
  __shared__ float acc_lds[4][GRP][HD];  // 8 KB

  if (tid < 64) {
    cs_lds[tid] = cos_cache[pos * 64 + tid];
    sn_lds[tid] = sin_cache[pos * 64 + tid];
  }
  if (tid >= 192 && tid < 192 + CHUNK / BS)
    bt[tid - 192] = block_tables[s * BPS + (t0 >> 4) + (tid - 192)];
  __syncthreads();

  // RoPE q (SCALE folded in) into LDS
  {
    const float* qp = q + (s * NH + kv * GRP) * HD;
#pragma unroll
    for (int j = tid; j < GRP * HD; j += 256) {
      int h = j >> 7, d = j & 127;
      float r;
      if (d < 64) r = qp[h * HD + d] * cs_lds[d] - qp[h * HD + d + 64] * sn_lds[d];
      else        r = qp[h * HD + d] * cs_lds[d - 64] + qp[h * HD + d - 64] * sn_lds[d - 64];
      qrot[j] = r * SCALE;
    }
  }
  if (has_new && tid < 128) {
    const float* kp = k_new + (s * NKV + kv) * HD;
    int d = tid;
    float r;
    if (d < 64) r = kp[d] * cs_lds[d] - kp[d + 64] * sn_lds[d];
    else        r = kp[d] * cs_lds[d - 64] + kp[d - 64] * sn_lds[d - 64];
    krot[d] = r;
  }
  __syncthreads();

  float4 qf0[GRP], qf1[GRP];
#pragma unroll
  for (int h = 0; h < GRP; ++h) {
    qf0[h] = *(const float4*)&qrot[h * HD + li * 4];
    qf1[h] = *(const float4*)&qrot[h * HD + 64 + li * 4];
  }

  // new-token score (local index == ncache), wave 0
  if (w == 0 && has_new) {
    float4 ka = *(const float4*)&krot[li * 4];
    float4 kb = *(const float4*)&krot[64 + li * 4];
    float p0 = red16(dot8(qf0[0], qf1[0], ka, kb));
    float p1 = red16(dot8(qf0[1], qf1[1], ka, kb));
    float p2 = red16(dot8(qf0[2], qf1[2], ka, kb));
    float p3 = red16(dot8(qf0[3], qf1[3], ka, kb));
    if (lane == 0) {
      s_sc[0][ncache] = p0; s_sc[1][ncache] = p1;
      s_sc[2][ncache] = p2; s_sc[3][ncache] = p3;
    }
  }

  // pass 1: QK^T over local cache tokens [0, ncache), 2-deep prefetch.
  // Packed cross-lane reduce: xor1/xor2 reduce 4-lane clusters (all heads),
  // then select head c=li&3 (invariant under xor4/8) and finish on one value.
  {
    int base = w * 4;
    if (base < ncache) {
      auto addr_of = [&](int j) -> int {
        int jc = j < ncache ? j : (ncache - 1);
        int blk = bt[jc >> 4];
        return ((blk * BS + (jc & 15)) * NKV + kv) * HD + li * 4;
      };
      int a = addr_of(base + sub);
      float4 ka = *(const float4*)&k_cache[a];
      float4 kb = *(const float4*)&k_cache[a + 64];
      const int c = li & 3;
      while (true) {
        int nbase = base + 16;
        bool more = nbase < ncache;     // wave-uniform
        float4 na, nb;
        if (more) {
          int an = addr_of(nbase + sub);
          na = *(const float4*)&k_cache[an];
          nb = *(const float4*)&k_cache[an + 64];
        }
        int j = base + sub;
        float p0 = dot8(qf0[0], qf1[0], ka, kb);
        float p1 = dot8(qf0[1], qf1[1], ka, kb);
        float p2 = dot8(qf0[2], qf1[2], ka, kb);
        float p3 = dot8(qf0[3], qf1[3], ka, kb);
        p0 += __shfl_xor(p0, 1); p1 += __shfl_xor(p1, 1);
        p2 += __shfl_xor(p2, 1); p3 += __shfl_xor(p3, 1);
        p0 += __shfl_xor(p0, 2); p1 += __shfl_xor(p1, 2);
        p2 += __shfl_xor(p2, 2); p3 += __shfl_xor(p3, 2);
        float x = (c == 0) ? p0 : (c == 1) ? p1 : (c == 2) ? p2 : p3;
        x += __shfl_xor(x, 4);
        x += __shfl_xor(x, 8);
        if (li < 4 && j < ncache) s_sc[li][j] = x;
        if (!more) break;
        base = nbase; ka = na; kb = nb;
      }
    }
  }
  __syncthreads();

  // softmax partial: wave w handles head w over [0, ntok)
  {
    float m = -3.0e38f;
    for (int t = lane; t < ntok; t += 64) m = fmaxf(m, s_sc[w][t]);
#pragma unroll
    for (int msk = 1; msk < 64; msk <<= 1) m = fmaxf(m, __shfl_xor(m, msk));
    float sum = 0.f;
    for (int t = lane; t < ntok; t += 64) {
      float p = __expf(s_sc[w][t] - m);
      s_sc[w][t] = p;
      sum += p;
    }
#pragma unroll
    for (int msk = 1; msk < 64; msk <<= 1) sum += __shfl_xor(sum, msk);
    if (lane == 0) {
      int part = ((s * NKV + kv) * GRP + w) * NSPLIT + sp;
      mlW[part] = make_float2(m, sum);
    }
  }
  __syncthreads();

  // pass 2: P·V over local cache tokens, 2-deep prefetch
  float4 aa0 = {0,0,0,0}, aa1 = {0,0,0,0}, aa2 = {0,0,0,0}, aa3 = {0,0,0,0};
  float4 ab0 = {0,0,0,0}, ab1 = {0,0,0,0}, ab2 = {0,0,0,0}, ab3 = {0,0,0,0};
  {
    int base = w * 4;
    if (base < ncache) {
      auto addr_of = [&](int j) -> int {
        int jc = j < ncache ? j : (ncache - 1);
        int blk = bt[jc >> 4];
        return ((blk * BS + (jc & 15)) * NKV + kv) * HD + li * 4;
      };
      int a = addr_of(base + sub);
      float4 va = *(const float4*)&v_cache[a];
      float4 vb = *(const float4*)&v_cache[a + 64];
      while (true) {
        int nbase = base + 16;
        bool more = nbase < ncache;
        float4 na, nb;
        if (more) {
          int an = addr_of(nbase + sub);
          na = *(const float4*)&v_cache[an];
          nb = *(const float4*)&v_cache[an + 64];
        }
        int j = base + sub;
        bool valid = j < ncache;
        float p0 = valid ? s_sc[0][j] : 0.f;
        float p1 = valid ? s_sc[1][j] : 0.f;
        float p2 = valid ? s_sc[2][j] : 0.f;
        float p3 = valid ? s_sc[3][j] : 0.f;
        aa0.x = fmaf(p0, va.x, aa0.x); aa0.y = fmaf(p0, va.y, aa0.y);
        aa0.z = fmaf(p0, va.z, aa0.z); aa0.w = fmaf(p0, va.w, aa0.w);
        ab0.x = fmaf(p0, vb.x, ab0.x); ab0.y = fmaf(p0, vb.y, ab0.y);
        ab0.z = fmaf(p0, vb.z, ab0.z); ab0.w = fmaf(p0, vb.w, ab0.w);
        aa1.x = fmaf(p1, va.x, aa1.x); aa1.y = fmaf(p1, va.y, aa1.y);
        aa1.z = fmaf(p1, va.z, aa1.z); aa1.w = fmaf(p1, va.w, aa1.w);
        ab1.x = fmaf(p1, vb.x, ab1.x); ab1.y = fmaf(p1, vb.y, ab1.y);
        ab1.z = fmaf(p1, vb.z, ab1.z); ab1.w = fmaf(p1, vb.w, ab1.w);
        aa2.x = fmaf(p2, va.x, aa2.x); aa2.y = fmaf(p2, va.y, aa2.y);
        aa2.z = fmaf(p2, va.z, aa2.z); aa2.w = fmaf(p2, va.w, aa2.w);
        ab2.x = fmaf(p2, vb.x, ab2.x); ab2.y = fmaf(p2, vb.y, ab2.y);
        ab2.z = fmaf(p2, vb.z, ab2.z); ab2.w = fmaf(p2, vb.w, ab2.w);
        aa3.x = fmaf(p3, va.x, aa3.x); aa3.y = fmaf(p3, va.y, aa3.y);
        aa3.z = fmaf(p3, va.z, aa3.z); aa3.w = fmaf(p3, va.w, aa3.w);
        ab3.x = fmaf(p3, vb.x, ab3.x); ab3.y = fmaf(p3, vb.y, ab3.y);
        ab3.z = fmaf(p3, vb.z, ab3.z); ab3.w = fmaf(p3, vb.w, ab3.w);
        if (!more) break;
        base = nbase; va = na; vb = nb;
      }
    }
  }
  red_sub(aa0); red_sub(aa1); red_sub(aa2); red_sub(aa3);
  red_sub(ab0); red_sub(ab1); red_sub(ab2); red_sub(ab3);
  if (lane < 16) {
    *(float4*)&acc_lds[w][0][li * 4] = aa0;
    *(float4*)&acc_lds[w][1][li * 4] = aa1;
    *(float4*)&acc_lds[w][2][li * 4] = aa2;
    *(float4*)&acc_lds[w][3][li * 4] = aa3;
    *(float4*)&acc_lds[w][0][64 + li * 4] = ab0;
    *(float4*)&acc_lds[w][1][64 + li * 4] = ab1;
    *(float4*)&acc_lds[w][2][64 + li * 4] = ab2;
    *(float4*)&acc_lds[w][3][64 + li * 4] = ab3;
  }
  __syncthreads();

  // epilogue: combine waves, add new-token V, write UNNORMALIZED partial
  {
    const float* vp = v_new + (s * NKV + kv) * HD;
#pragma unroll
    for (int j = tid; j < GRP * HD; j += 256) {
      int h = j >> 7, d = j & 127;
      float o = acc_lds[0][h][d] + acc_lds[1][h][d] + acc_lds[2][h][d] + acc_lds[3][h][d];
      if (has_new) o = fmaf(s_sc[h][ncache], vp[d], o);
      int part = ((s * NKV + kv) * GRP + h) * NSPLIT + sp;
      accW[part * HD + d] = o;
    }
  }
}

// LSE-combine the per-split partials. One wave per (seq, head).
extern "C" __global__ __launch_bounds__(256, 8)
void paged_reduce(const float* __restrict__ accW,
                  const float2* __restrict__ mlW,
                  const int* __restrict__ context_lens,
                  float* __restrict__ out)
{
  const int tid  = threadIdx.x;
  const int lane = tid & 63;
  const int w    = tid >> 6;
  const int idx  = blockIdx.x * 4 + w;   // 0..1023 = (s, h)
  const int s    = idx >> 5;
  const int h    = idx & 31;
  const int kv   = h >> 2, g = h & 3;
  const int ctx  = context_lens[s];
  const int nsp  = (ctx + CHUNK - 1) / CHUNK;
  const int pbase = ((s * NKV + kv) * GRP + g) * NSPLIT;

  float m = -3.0e38f;
  for (int i = 0; i < nsp; ++i) m = fmaxf(m, mlW[pbase + i].x);
  float L = 0.f;
  float2 acc = {0.f, 0.f};
  for (int i = 0; i < nsp; ++i) {
    float2 ml = mlW[pbase + i];
    float sc = __expf(ml.x - m);
    L += ml.y * sc;
    float2 a = *(const float2*)&accW[(pbase + i) * HD + lane * 2];
    acc.x = fmaf(a.x, sc, acc.x);
    acc.y = fmaf(a.y, sc, acc.y);
  }
  float inv = 1.0f / L;
  float2 o = make_float2(acc.x * inv, acc.y * inv);
  *(float2*)&out[(s * NH + h) * HD + lane * 2] = o;
}

extern "C" void kernel_launch(void* const* d_in, const int* in_sizes, int n_in,
                              void* d_out, int out_size, void* d_ws, size_t ws_size,
                              hipStream_t stream) {
  const float* q         = (const float*)d_in[0];
  const float* k_new     = (const float*)d_in[1];
  const float* v_new     = (const float*)d_in[2];
  const float* k_cache   = (const float*)d_in[3];
  const float* v_cache   = (const float*)d_in[4];
  const float* cos_cache = (const float*)d_in[5];
  const float* sin_cache = (const float*)d_in[6];
  const int* block_tables = (const int*)d_in[9];
  const int* context_lens = (const int*)d_in[10];
  float* out = (float*)d_out;

  float*  accW = (float*)d_ws;   // NSEQ*NKV*GRP*NSPLIT*HD floats = 8 MB
  float2* mlW  = (float2*)((char*)d_ws + (size_t)NSEQ * NKV * GRP * NSPLIT * HD * sizeof(float));

  dim3 grid(NKV, NSEQ, NSPLIT);
  paged_split<<<grid, 256, 0, stream>>>(q, k_new, v_new, k_cache, v_cache,
                                        cos_cache, sin_cache, block_tables,
                                        context_lens, accW, mlW);
  paged_reduce<<<NSEQ * NH / 4, 256, 0, stream>>>(accW, mlW, context_lens, out);
}

// Round 5
// 64.967 us; speedup vs baseline: 1.2712x; 1.2712x over previous
//
#include <hip/hip_runtime.h>

#define NSEQ 32
#define NH 32
#define NKV 8
#define GRP 4
#define HD 128
#define BS 16
#define MAXCTX 2048
#define BPS 128
#define CHUNK 256
#define NSPLIT (MAXCTX / CHUNK)   // 8
#define SCALE 0.08838834764831845f

__device__ __forceinline__ float dot8(float4 qa, float4 qb, float4 ka, float4 kb) {
  float r = qa.x * ka.x;
  r = fmaf(qa.y, ka.y, r);
  r = fmaf(qa.z, ka.z, r);
  r = fmaf(qa.w, ka.w, r);
  r = fmaf(qb.x, kb.x, r);
  r = fmaf(qb.y, kb.y, r);
  r = fmaf(qb.z, kb.z, r);
  r = fmaf(qb.w, kb.w, r);
  return r;
}

__device__ __forceinline__ float red16(float x) {
  x += __shfl_xor(x, 1);
  x += __shfl_xor(x, 2);
  x += __shfl_xor(x, 4);
  x += __shfl_xor(x, 8);
  return x;
}

__device__ __forceinline__ void red_sub(float4& v) {
  v.x += __shfl_xor(v.x, 16); v.y += __shfl_xor(v.y, 16);
  v.z += __shfl_xor(v.z, 16); v.w += __shfl_xor(v.w, 16);
  v.x += __shfl_xor(v.x, 32); v.y += __shfl_xor(v.y, 32);
  v.z += __shfl_xor(v.z, 32); v.w += __shfl_xor(v.w, 32);
}

// One workgroup per (kv-head, seq, ctx-split). Produces an UNNORMALIZED
// partial (m, l, acc[GRP][HD]) for its 256-token chunk, flash-decode style.
// No manual prefetch: rely on 8 blocks/CU (VGPR<=64) TLP for latency hiding.
extern "C" __global__ __launch_bounds__(256, 8)
void paged_split(const float* __restrict__ q,
                 const float* __restrict__ k_new,
                 const float* __restrict__ v_new,
                 const float* __restrict__ k_cache,
                 const float* __restrict__ v_cache,
                 const float* __restrict__ cos_cache,
                 const float* __restrict__ sin_cache,
                 const int* __restrict__ block_tables,
                 const int* __restrict__ context_lens,
                 float* __restrict__ accW,
                 float2* __restrict__ mlW)
{
  const int kv = blockIdx.x;   // 0..7
  const int s  = blockIdx.y;   // 0..31
  const int sp = blockIdx.z;   // 0..7
  const int ctx = context_lens[s];
  const int t0  = sp * CHUNK;
  if (t0 >= ctx) return;                      // inactive split: never read by reduce
  const int tend = min(t0 + CHUNK, ctx);
  const int ntok = tend - t0;                 // tokens this split handles (incl. new)
  const int pos  = ctx - 1;                   // the new token's position
  const bool has_new = (pos >= t0) && (pos < tend);   // ONLY the split containing ctx-1
  const int ncache = has_new ? (pos - t0) : ntok;     // local cache-token count

  const int tid  = threadIdx.x;
  const int lane = tid & 63;
  const int w    = tid >> 6;
  const int sub  = lane >> 4;
  const int li   = lane & 15;

  __shared__ float cs_lds[64];
  __shared__ float sn_lds[64];
  __shared__ float qrot[GRP * HD];       // 2 KB
  __shared__ float krot[HD];             // 512 B
  __shared__ int   bt[CHUNK / BS];       // 16 entries
  __shared__ float s_sc[GRP][CHUNK];     // 4 KB (scores -> p)
  __shared__ float acc_lds[4][GRP][HD];  // 8 KB

  if (tid < 64) {
    cs_lds[tid] = cos_cache[pos * 64 + tid];
    sn_lds[tid] = sin_cache[pos * 64 + tid];
  }
  if (tid >= 192 && tid < 192 + CHUNK / BS)
    bt[tid - 192] = block_tables[s * BPS + (t0 >> 4) + (tid - 192)];
  __syncthreads();

  // RoPE q (SCALE folded in) into LDS
  {
    const float* qp = q + (s * NH + kv * GRP) * HD;
#pragma unroll
    for (int j = tid; j < GRP * HD; j += 256) {
      int h = j >> 7, d = j & 127;
      float r;
      if (d < 64) r = qp[h * HD + d] * cs_lds[d] - qp[h * HD + d + 64] * sn_lds[d];
      else        r = qp[h * HD + d] * cs_lds[d - 64] + qp[h * HD + d - 64] * sn_lds[d - 64];
      qrot[j] = r * SCALE;
    }
  }
  if (has_new && tid < 128) {
    const float* kp = k_new + (s * NKV + kv) * HD;
    int d = tid;
    float r;
    if (d < 64) r = kp[d] * cs_lds[d] - kp[d + 64] * sn_lds[d];
    else        r = kp[d] * cs_lds[d - 64] + kp[d - 64] * sn_lds[d - 64];
    krot[d] = r;
  }
  __syncthreads();

  float4 qf0[GRP], qf1[GRP];
#pragma unroll
  for (int h = 0; h < GRP; ++h) {
    qf0[h] = *(const float4*)&qrot[h * HD + li * 4];
    qf1[h] = *(const float4*)&qrot[h * HD + 64 + li * 4];
  }

  // new-token score (local index == ncache), wave 0
  if (w == 0 && has_new) {
    float4 ka = *(const float4*)&krot[li * 4];
    float4 kb = *(const float4*)&krot[64 + li * 4];
    float p0 = red16(dot8(qf0[0], qf1[0], ka, kb));
    float p1 = red16(dot8(qf0[1], qf1[1], ka, kb));
    float p2 = red16(dot8(qf0[2], qf1[2], ka, kb));
    float p3 = red16(dot8(qf0[3], qf1[3], ka, kb));
    if (lane == 0) {
      s_sc[0][ncache] = p0; s_sc[1][ncache] = p1;
      s_sc[2][ncache] = p2; s_sc[3][ncache] = p3;
    }
  }

  // pass 1: QK^T over local cache tokens [0, ncache).
  // Packed cross-lane reduce: xor1/xor2 reduce 4-lane clusters (all heads),
  // then select head c=li&3 (invariant under xor4/8) and finish on one value.
  {
    const int c = li & 3;
    for (int j0 = w * 4; j0 < ncache; j0 += 16) {
      int j = j0 + sub;
      int jc = j < ncache ? j : (ncache - 1);
      int blk = bt[jc >> 4];
      int a = ((blk * BS + (jc & 15)) * NKV + kv) * HD + li * 4;
      float4 ka = *(const float4*)&k_cache[a];
      float4 kb = *(const float4*)&k_cache[a + 64];
      float p0 = dot8(qf0[0], qf1[0], ka, kb);
      float p1 = dot8(qf0[1], qf1[1], ka, kb);
      float p2 = dot8(qf0[2], qf1[2], ka, kb);
      float p3 = dot8(qf0[3], qf1[3], ka, kb);
      p0 += __shfl_xor(p0, 1); p1 += __shfl_xor(p1, 1);
      p2 += __shfl_xor(p2, 1); p3 += __shfl_xor(p3, 1);
      p0 += __shfl_xor(p0, 2); p1 += __shfl_xor(p1, 2);
      p2 += __shfl_xor(p2, 2); p3 += __shfl_xor(p3, 2);
      float x = (c == 0) ? p0 : (c == 1) ? p1 : (c == 2) ? p2 : p3;
      x += __shfl_xor(x, 4);
      x += __shfl_xor(x, 8);
      if (li < 4 && j < ncache) s_sc[li][j] = x;
    }
  }
  __syncthreads();

  // softmax partial: wave w handles head w over [0, ntok)
  {
    float m = -3.0e38f;
    for (int t = lane; t < ntok; t += 64) m = fmaxf(m, s_sc[w][t]);
#pragma unroll
    for (int msk = 1; msk < 64; msk <<= 1) m = fmaxf(m, __shfl_xor(m, msk));
    float sum = 0.f;
    for (int t = lane; t < ntok; t += 64) {
      float p = __expf(s_sc[w][t] - m);
      s_sc[w][t] = p;
      sum += p;
    }
#pragma unroll
    for (int msk = 1; msk < 64; msk <<= 1) sum += __shfl_xor(sum, msk);
    if (lane == 0) {
      int part = ((s * NKV + kv) * GRP + w) * NSPLIT + sp;
      mlW[part] = make_float2(m, sum);
    }
  }
  __syncthreads();

  // pass 2: P·V over local cache tokens
  float4 aa0 = {0,0,0,0}, aa1 = {0,0,0,0}, aa2 = {0,0,0,0}, aa3 = {0,0,0,0};
  float4 ab0 = {0,0,0,0}, ab1 = {0,0,0,0}, ab2 = {0,0,0,0}, ab3 = {0,0,0,0};
  for (int j0 = w * 4; j0 < ncache; j0 += 16) {
    int j = j0 + sub;
    int jc = j < ncache ? j : (ncache - 1);
    int blk = bt[jc >> 4];
    int a = ((blk * BS + (jc & 15)) * NKV + kv) * HD + li * 4;
    float4 va = *(const float4*)&v_cache[a];
    float4 vb = *(const float4*)&v_cache[a + 64];
    bool valid = j < ncache;
    float p0 = valid ? s_sc[0][j] : 0.f;
    float p1 = valid ? s_sc[1][j] : 0.f;
    float p2 = valid ? s_sc[2][j] : 0.f;
    float p3 = valid ? s_sc[3][j] : 0.f;
    aa0.x = fmaf(p0, va.x, aa0.x); aa0.y = fmaf(p0, va.y, aa0.y);
    aa0.z = fmaf(p0, va.z, aa0.z); aa0.w = fmaf(p0, va.w, aa0.w);
    ab0.x = fmaf(p0, vb.x, ab0.x); ab0.y = fmaf(p0, vb.y, ab0.y);
    ab0.z = fmaf(p0, vb.z, ab0.z); ab0.w = fmaf(p0, vb.w, ab0.w);
    aa1.x = fmaf(p1, va.x, aa1.x); aa1.y = fmaf(p1, va.y, aa1.y);
    aa1.z = fmaf(p1, va.z, aa1.z); aa1.w = fmaf(p1, va.w, aa1.w);
    ab1.x = fmaf(p1, vb.x, ab1.x); ab1.y = fmaf(p1, vb.y, ab1.y);
    ab1.z = fmaf(p1, vb.z, ab1.z); ab1.w = fmaf(p1, vb.w, ab1.w);
    aa2.x = fmaf(p2, va.x, aa2.x); aa2.y = fmaf(p2, va.y, aa2.y);
    aa2.z = fmaf(p2, va.z, aa2.z); aa2.w = fmaf(p2, va.w, aa2.w);
    ab2.x = fmaf(p2, vb.x, ab2.x); ab2.y = fmaf(p2, vb.y, ab2.y);
    ab2.z = fmaf(p2, vb.z, ab2.z); ab2.w = fmaf(p2, vb.w, ab2.w);
    aa3.x = fmaf(p3, va.x, aa3.x); aa3.y = fmaf(p3, va.y, aa3.y);
    aa3.z = fmaf(p3, va.z, aa3.z); aa3.w = fmaf(p3, va.w, aa3.w);
    ab3.x = fmaf(p3, vb.x, ab3.x); ab3.y = fmaf(p3, vb.y, ab3.y);
    ab3.z = fmaf(p3, vb.z, ab3.z); ab3.w = fmaf(p3, vb.w, ab3.w);
  }
  red_sub(aa0); red_sub(aa1); red_sub(aa2); red_sub(aa3);
  red_sub(ab0); red_sub(ab1); red_sub(ab2); red_sub(ab3);
  if (lane < 16) {
    *(float4*)&acc_lds[w][0][li * 4] = aa0;
    *(float4*)&acc_lds[w][1][li * 4] = aa1;
    *(float4*)&acc_lds[w][2][li * 4] = aa2;
    *(float4*)&acc_lds[w][3][li * 4] = aa3;
    *(float4*)&acc_lds[w][0][64 + li * 4] = ab0;
    *(float4*)&acc_lds[w][1][64 + li * 4] = ab1;
    *(float4*)&acc_lds[w][2][64 + li * 4] = ab2;
    *(float4*)&acc_lds[w][3][64 + li * 4] = ab3;
  }
  __syncthreads();

  // epilogue: combine waves, add new-token V, write UNNORMALIZED partial
  {
    const float* vp = v_new + (s * NKV + kv) * HD;
#pragma unroll
    for (int j = tid; j < GRP * HD; j += 256) {
      int h = j >> 7, d = j & 127;
      float o = acc_lds[0][h][d] + acc_lds[1][h][d] + acc_lds[2][h][d] + acc_lds[3][h][d];
      if (has_new) o = fmaf(s_sc[h][ncache], vp[d], o);
      int part = ((s * NKV + kv) * GRP + h) * NSPLIT + sp;
      accW[part * HD + d] = o;
    }
  }
}

// LSE-combine the per-split partials. One wave per (seq, head).
extern "C" __global__ __launch_bounds__(256, 8)
void paged_reduce(const float* __restrict__ accW,
                  const float2* __restrict__ mlW,
                  const int* __restrict__ context_lens,
                  float* __restrict__ out)
{
  const int tid  = threadIdx.x;
  const int lane = tid & 63;
  const int w    = tid >> 6;
  const int idx  = blockIdx.x * 4 + w;   // 0..1023 = (s, h)
  const int s    = idx >> 5;
  const int h    = idx & 31;
  const int kv   = h >> 2, g = h & 3;
  const int ctx  = context_lens[s];
  const int nsp  = (ctx + CHUNK - 1) / CHUNK;
  const int pbase = ((s * NKV + kv) * GRP + g) * NSPLIT;

  float m = -3.0e38f;
  for (int i = 0; i < nsp; ++i) m = fmaxf(m, mlW[pbase + i].x);
  float L = 0.f;
  float2 acc = {0.f, 0.f};
  for (int i = 0; i < nsp; ++i) {
    float2 ml = mlW[pbase + i];
    float sc = __expf(ml.x - m);
    L += ml.y * sc;
    float2 a = *(const float2*)&accW[(pbase + i) * HD + lane * 2];
    acc.x = fmaf(a.x, sc, acc.x);
    acc.y = fmaf(a.y, sc, acc.y);
  }
  float inv = 1.0f / L;
  float2 o = make_float2(acc.x * inv, acc.y * inv);
  *(float2*)&out[(s * NH + h) * HD + lane * 2] = o;
}

extern "C" void kernel_launch(void* const* d_in, const int* in_sizes, int n_in,
                              void* d_out, int out_size, void* d_ws, size_t ws_size,
                              hipStream_t stream) {
  const float* q         = (const float*)d_in[0];
  const float* k_new     = (const float*)d_in[1];
  const float* v_new     = (const float*)d_in[2];
  const float* k_cache   = (const float*)d_in[3];
  const float* v_cache   = (const float*)d_in[4];
  const float* cos_cache = (const float*)d_in[5];
  const float* sin_cache = (const float*)d_in[6];
  const int* block_tables = (const int*)d_in[9];
  const int* context_lens = (const int*)d_in[10];
  float* out = (float*)d_out;

  float*  accW = (float*)d_ws;   // NSEQ*NKV*GRP*NSPLIT*HD floats = 4 MB
  float2* mlW  = (float2*)((char*)d_ws + (size_t)NSEQ * NKV * GRP * NSPLIT * HD * sizeof(float));

  dim3 grid(NKV, NSEQ, NSPLIT);
  paged_split<<<grid, 256, 0, stream>>>(q, k_new, v_new, k_cache, v_cache,
                                        cos_cache, sin_cache, block_tables,
                                        context_lens, accW, mlW);
  paged_reduce<<<NSEQ * NH / 4, 256, 0, stream>>>(accW, mlW, context_lens, out);
}

// Round 6
// 58.148 us; speedup vs baseline: 1.4203x; 1.1173x over previous
//
#include <hip/hip_runtime.h>

#define NSEQ 32
#define NH 32
#define NKV 8
#define GRP 4
#define HD 128
#define BS 16
#define MAXCTX 2048
#define BPS 128
#define CHUNK 256
#define NSPLIT (MAXCTX / CHUNK)   // 8
#define SCALE 0.08838834764831845f

__device__ __forceinline__ float dot8(float4 qa, float4 qb, float4 ka, float4 kb) {
  float r = qa.x * ka.x;
  r = fmaf(qa.y, ka.y, r);
  r = fmaf(qa.z, ka.z, r);
  r = fmaf(qa.w, ka.w, r);
  r = fmaf(qb.x, kb.x, r);
  r = fmaf(qb.y, kb.y, r);
  r = fmaf(qb.z, kb.z, r);
  r = fmaf(qb.w, kb.w, r);
  return r;
}

__device__ __forceinline__ float red16(float x) {
  x += __shfl_xor(x, 1);
  x += __shfl_xor(x, 2);
  x += __shfl_xor(x, 4);
  x += __shfl_xor(x, 8);
  return x;
}

__device__ __forceinline__ void red_sub(float4& v) {
  v.x += __shfl_xor(v.x, 16); v.y += __shfl_xor(v.y, 16);
  v.z += __shfl_xor(v.z, 16); v.w += __shfl_xor(v.w, 16);
  v.x += __shfl_xor(v.x, 32); v.y += __shfl_xor(v.y, 32);
  v.z += __shfl_xor(v.z, 32); v.w += __shfl_xor(v.w, 32);
}

// One workgroup per (kv-head, dense-active-split). Block scans context_lens to
// map its dense index -> (seq, split); inactive tail blocks exit immediately.
// Produces an UNNORMALIZED partial (m, l, acc[GRP][HD]) per 256-token chunk.
extern "C" __global__ __launch_bounds__(256, 8)
void paged_split(const float* __restrict__ q,
                 const float* __restrict__ k_new,
                 const float* __restrict__ v_new,
                 const float* __restrict__ k_cache,
                 const float* __restrict__ v_cache,
                 const float* __restrict__ cos_cache,
                 const float* __restrict__ sin_cache,
                 const int* __restrict__ block_tables,
                 const int* __restrict__ context_lens,
                 float* __restrict__ accW,
                 float2* __restrict__ mlW)
{
  const int kv = blockIdx.x;   // 0..7
  // ---- dense remap: a -> (s, sp), wave-uniform scan ----
  int s = -1, sp = blockIdx.y;
  for (int i = 0; i < NSEQ; ++i) {
    int ns = (context_lens[i] + CHUNK - 1) / CHUNK;
    if (sp < ns) { s = i; break; }
    sp -= ns;
  }
  if (s < 0) return;                          // past total active splits

  const int ctx = context_lens[s];
  const int t0  = sp * CHUNK;                 // guaranteed < ctx by remap
  const int tend = min(t0 + CHUNK, ctx);
  const int ntok = tend - t0;                 // tokens this split handles (incl. new)
  const int pos  = ctx - 1;                   // the new token's position
  const bool has_new = (pos >= t0) && (pos < tend);   // ONLY the split containing ctx-1
  const int ncache = has_new ? (pos - t0) : ntok;     // local cache-token count

  const int tid  = threadIdx.x;
  const int lane = tid & 63;
  const int w    = tid >> 6;
  const int sub  = lane >> 4;
  const int li   = lane & 15;

  __shared__ float cs_lds[64];
  __shared__ float sn_lds[64];
  __shared__ float qrot[GRP * HD];       // 2 KB
  __shared__ float krot[HD];             // 512 B
  __shared__ int   bt[CHUNK / BS];       // 16 entries
  __shared__ float s_sc[GRP][CHUNK];     // 4 KB (scores -> p)
  __shared__ float acc_lds[4][GRP][HD];  // 8 KB

  if (tid < 64) {
    cs_lds[tid] = cos_cache[pos * 64 + tid];
    sn_lds[tid] = sin_cache[pos * 64 + tid];
  }
  if (tid >= 192 && tid < 192 + CHUNK / BS)
    bt[tid - 192] = block_tables[s * BPS + (t0 >> 4) + (tid - 192)];
  __syncthreads();

  // RoPE q (SCALE folded in) into LDS
  {
    const float* qp = q + (s * NH + kv * GRP) * HD;
#pragma unroll
    for (int j = tid; j < GRP * HD; j += 256) {
      int h = j >> 7, d = j & 127;
      float r;
      if (d < 64) r = qp[h * HD + d] * cs_lds[d] - qp[h * HD + d + 64] * sn_lds[d];
      else        r = qp[h * HD + d] * cs_lds[d - 64] + qp[h * HD + d - 64] * sn_lds[d - 64];
      qrot[j] = r * SCALE;
    }
  }
  if (has_new && tid < 128) {
    const float* kp = k_new + (s * NKV + kv) * HD;
    int d = tid;
    float r;
    if (d < 64) r = kp[d] * cs_lds[d] - kp[d + 64] * sn_lds[d];
    else        r = kp[d] * cs_lds[d - 64] + kp[d - 64] * sn_lds[d - 64];
    krot[d] = r;
  }
  __syncthreads();

  float4 qf0[GRP], qf1[GRP];
#pragma unroll
  for (int h = 0; h < GRP; ++h) {
    qf0[h] = *(const float4*)&qrot[h * HD + li * 4];
    qf1[h] = *(const float4*)&qrot[h * HD + 64 + li * 4];
  }

  // new-token score (local index == ncache), wave 0
  if (w == 0 && has_new) {
    float4 ka = *(const float4*)&krot[li * 4];
    float4 kb = *(const float4*)&krot[64 + li * 4];
    float p0 = red16(dot8(qf0[0], qf1[0], ka, kb));
    float p1 = red16(dot8(qf0[1], qf1[1], ka, kb));
    float p2 = red16(dot8(qf0[2], qf1[2], ka, kb));
    float p3 = red16(dot8(qf0[3], qf1[3], ka, kb));
    if (lane == 0) {
      s_sc[0][ncache] = p0; s_sc[1][ncache] = p1;
      s_sc[2][ncache] = p2; s_sc[3][ncache] = p3;
    }
  }

  // pass 1: QK^T over local cache tokens [0, ncache).
  // Packed cross-lane reduce: xor1/xor2 reduce 4-lane clusters (all heads),
  // then select head c=li&3 (invariant under xor4/8) and finish on one value.
  {
    const int c = li & 3;
    for (int j0 = w * 4; j0 < ncache; j0 += 16) {
      int j = j0 + sub;
      int jc = j < ncache ? j : (ncache - 1);
      int blk = bt[jc >> 4];
      int a = ((blk * BS + (jc & 15)) * NKV + kv) * HD + li * 4;
      float4 ka = *(const float4*)&k_cache[a];
      float4 kb = *(const float4*)&k_cache[a + 64];
      float p0 = dot8(qf0[0], qf1[0], ka, kb);
      float p1 = dot8(qf0[1], qf1[1], ka, kb);
      float p2 = dot8(qf0[2], qf1[2], ka, kb);
      float p3 = dot8(qf0[3], qf1[3], ka, kb);
      p0 += __shfl_xor(p0, 1); p1 += __shfl_xor(p1, 1);
      p2 += __shfl_xor(p2, 1); p3 += __shfl_xor(p3, 1);
      p0 += __shfl_xor(p0, 2); p1 += __shfl_xor(p1, 2);
      p2 += __shfl_xor(p2, 2); p3 += __shfl_xor(p3, 2);
      float x = (c == 0) ? p0 : (c == 1) ? p1 : (c == 2) ? p2 : p3;
      x += __shfl_xor(x, 4);
      x += __shfl_xor(x, 8);
      if (li < 4 && j < ncache) s_sc[li][j] = x;
    }
  }
  __syncthreads();

  // softmax partial: wave w handles head w over [0, ntok)
  {
    float m = -3.0e38f;
    for (int t = lane; t < ntok; t += 64) m = fmaxf(m, s_sc[w][t]);
#pragma unroll
    for (int msk = 1; msk < 64; msk <<= 1) m = fmaxf(m, __shfl_xor(m, msk));
    float sum = 0.f;
    for (int t = lane; t < ntok; t += 64) {
      float p = __expf(s_sc[w][t] - m);
      s_sc[w][t] = p;
      sum += p;
    }
#pragma unroll
    for (int msk = 1; msk < 64; msk <<= 1) sum += __shfl_xor(sum, msk);
    if (lane == 0) {
      int part = ((s * NKV + kv) * GRP + w) * NSPLIT + sp;
      mlW[part] = make_float2(m, sum);
    }
  }
  __syncthreads();

  // pass 2: P·V over local cache tokens
  float4 aa0 = {0,0,0,0}, aa1 = {0,0,0,0}, aa2 = {0,0,0,0}, aa3 = {0,0,0,0};
  float4 ab0 = {0,0,0,0}, ab1 = {0,0,0,0}, ab2 = {0,0,0,0}, ab3 = {0,0,0,0};
  for (int j0 = w * 4; j0 < ncache; j0 += 16) {
    int j = j0 + sub;
    int jc = j < ncache ? j : (ncache - 1);
    int blk = bt[jc >> 4];
    int a = ((blk * BS + (jc & 15)) * NKV + kv) * HD + li * 4;
    float4 va = *(const float4*)&v_cache[a];
    float4 vb = *(const float4*)&v_cache[a + 64];
    bool valid = j < ncache;
    float p0 = valid ? s_sc[0][j] : 0.f;
    float p1 = valid ? s_sc[1][j] : 0.f;
    float p2 = valid ? s_sc[2][j] : 0.f;
    float p3 = valid ? s_sc[3][j] : 0.f;
    aa0.x = fmaf(p0, va.x, aa0.x); aa0.y = fmaf(p0, va.y, aa0.y);
    aa0.z = fmaf(p0, va.z, aa0.z); aa0.w = fmaf(p0, va.w, aa0.w);
    ab0.x = fmaf(p0, vb.x, ab0.x); ab0.y = fmaf(p0, vb.y, ab0.y);
    ab0.z = fmaf(p0, vb.z, ab0.z); ab0.w = fmaf(p0, vb.w, ab0.w);
    aa1.x = fmaf(p1, va.x, aa1.x); aa1.y = fmaf(p1, va.y, aa1.y);
    aa1.z = fmaf(p1, va.z, aa1.z); aa1.w = fmaf(p1, va.w, aa1.w);
    ab1.x = fmaf(p1, vb.x, ab1.x); ab1.y = fmaf(p1, vb.y, ab1.y);
    ab1.z = fmaf(p1, vb.z, ab1.z); ab1.w = fmaf(p1, vb.w, ab1.w);
    aa2.x = fmaf(p2, va.x, aa2.x); aa2.y = fmaf(p2, va.y, aa2.y);
    aa2.z = fmaf(p2, va.z, aa2.z); aa2.w = fmaf(p2, va.w, aa2.w);
    ab2.x = fmaf(p2, vb.x, ab2.x); ab2.y = fmaf(p2, vb.y, ab2.y);
    ab2.z = fmaf(p2, vb.z, ab2.z); ab2.w = fmaf(p2, vb.w, ab2.w);
    aa3.x = fmaf(p3, va.x, aa3.x); aa3.y = fmaf(p3, va.y, aa3.y);
    aa3.z = fmaf(p3, va.z, aa3.z); aa3.w = fmaf(p3, va.w, aa3.w);
    ab3.x = fmaf(p3, vb.x, ab3.x); ab3.y = fmaf(p3, vb.y, ab3.y);
    ab3.z = fmaf(p3, vb.z, ab3.z); ab3.w = fmaf(p3, vb.w, ab3.w);
  }
  red_sub(aa0); red_sub(aa1); red_sub(aa2); red_sub(aa3);
  red_sub(ab0); red_sub(ab1); red_sub(ab2); red_sub(ab3);
  if (lane < 16) {
    *(float4*)&acc_lds[w][0][li * 4] = aa0;
    *(float4*)&acc_lds[w][1][li * 4] = aa1;
    *(float4*)&acc_lds[w][2][li * 4] = aa2;
    *(float4*)&acc_lds[w][3][li * 4] = aa3;
    *(float4*)&acc_lds[w][0][64 + li * 4] = ab0;
    *(float4*)&acc_lds[w][1][64 + li * 4] = ab1;
    *(float4*)&acc_lds[w][2][64 + li * 4] = ab2;
    *(float4*)&acc_lds[w][3][64 + li * 4] = ab3;
  }
  __syncthreads();

  // epilogue: combine waves, add new-token V, write UNNORMALIZED partial
  {
    const float* vp = v_new + (s * NKV + kv) * HD;
#pragma unroll
    for (int j = tid; j < GRP * HD; j += 256) {
      int h = j >> 7, d = j & 127;
      float o = acc_lds[0][h][d] + acc_lds[1][h][d] + acc_lds[2][h][d] + acc_lds[3][h][d];
      if (has_new) o = fmaf(s_sc[h][ncache], vp[d], o);
      int part = ((s * NKV + kv) * GRP + h) * NSPLIT + sp;
      accW[part * HD + d] = o;
    }
  }
}

// LSE-combine the per-split partials. One wave per (seq, head).
extern "C" __global__ __launch_bounds__(256, 8)
void paged_reduce(const float* __restrict__ accW,
                  const float2* __restrict__ mlW,
                  const int* __restrict__ context_lens,
                  float* __restrict__ out)
{
  const int tid  = threadIdx.x;
  const int lane = tid & 63;
  const int w    = tid >> 6;
  const int idx  = blockIdx.x * 4 + w;   // 0..1023 = (s, h)
  const int s    = idx >> 5;
  const int h    = idx & 31;
  const int kv   = h >> 2, g = h & 3;
  const int ctx  = context_lens[s];
  const int nsp  = (ctx + CHUNK - 1) / CHUNK;
  const int pbase = ((s * NKV + kv) * GRP + g) * NSPLIT;

  float m = -3.0e38f;
  for (int i = 0; i < nsp; ++i) m = fmaxf(m, mlW[pbase + i].x);
  float L = 0.f;
  float2 acc = {0.f, 0.f};
  for (int i = 0; i < nsp; ++i) {
    float2 ml = mlW[pbase + i];
    float sc = __expf(ml.x - m);
    L += ml.y * sc;
    float2 a = *(const float2*)&accW[(pbase + i) * HD + lane * 2];
    acc.x = fmaf(a.x, sc, acc.x);
    acc.y = fmaf(a.y, sc, acc.y);
  }
  float inv = 1.0f / L;
  float2 o = make_float2(acc.x * inv, acc.y * inv);
  *(float2*)&out[(s * NH + h) * HD + lane * 2] = o;
}

extern "C" void kernel_launch(void* const* d_in, const int* in_sizes, int n_in,
                              void* d_out, int out_size, void* d_ws, size_t ws_size,
                              hipStream_t stream) {
  const float* q         = (const float*)d_in[0];
  const float* k_new     = (const float*)d_in[1];
  const float* v_new     = (const float*)d_in[2];
  const float* k_cache   = (const float*)d_in[3];
  const float* v_cache   = (const float*)d_in[4];
  const float* cos_cache = (const float*)d_in[5];
  const float* sin_cache = (const float*)d_in[6];
  const int* block_tables = (const int*)d_in[9];
  const int* context_lens = (const int*)d_in[10];
  float* out = (float*)d_out;

  float*  accW = (float*)d_ws;   // NSEQ*NKV*GRP*NSPLIT*HD floats = 4 MB
  float2* mlW  = (float2*)((char*)d_ws + (size_t)NSEQ * NKV * GRP * NSPLIT * HD * sizeof(float));

  dim3 grid(NKV, NSEQ * NSPLIT);   // y = dense active-split index (max 256)
  paged_split<<<grid, 256, 0, stream>>>(q, k_new, v_new, k_cache, v_cache,
                                        cos_cache, sin_cache, block_tables,
                                        context_lens, accW, mlW);
  paged_reduce<<<NSEQ * NH / 4, 256, 0, stream>>>(accW, mlW, context_lens, out);
}